// Round 2
// baseline (1097104.004 us; speedup 1.0000x reference)
//
#include <hip/hip_runtime.h>
#include <hip/hip_fp16.h>
#include <math.h>

typedef unsigned int  uint32;
typedef unsigned short u16;

#define NWG 65          // 1 sequential WG + 64 helper WGs
#define NTH 256

// workspace layout (bytes)
#define OFF_XP   1024u                        // xp buffer [256][768] f32
#define OFF_XC   (OFF_XP + 256u*768u*4u)      // Xc / seq / Xr buffer [256][256] f32
#define OFF_D    (OFF_XC + 256u*256u*4u)      // dec_out row buffer [256][256] f32
#define OFF_Y1   (OFF_D  + 256u*256u*4u)      // y1 [128][512] f32

typedef _Float16 half2_t __attribute__((ext_vector_type(2)));

__device__ __forceinline__ float fdot2f(uint32 w, uint32 h, float acc) {
#if __has_builtin(__builtin_amdgcn_fdot2)
  return __builtin_amdgcn_fdot2(__builtin_bit_cast(half2_t, w),
                                __builtin_bit_cast(half2_t, h), acc, false);
#else
  half2_t a = __builtin_bit_cast(half2_t, w);
  half2_t b = __builtin_bit_cast(half2_t, h);
  return acc + (float)a[0]*(float)b[0] + (float)a[1]*(float)b[1];
#endif
}

__device__ __forceinline__ uint32 pack_h2(float x, float y) {
  _Float16 hx = (_Float16)x, hy = (_Float16)y;
  u16 ux = __builtin_bit_cast(u16, hx);
  u16 uy = __builtin_bit_cast(u16, hy);
  return (uint32)ux | ((uint32)uy << 16);
}

__device__ __forceinline__ float sigm(float x) { return 1.0f/(1.0f + expf(-x)); }

// Load one GRU's W_hh (f32 [768][256]): lane i owns rows i (r), 256+i (z),
// 512+i (n), each packed to 128 uint32 of f16 pairs. 384 VGPRs/lane.
__device__ __forceinline__ void load_weights(
    const float* __restrict__ whh, const float* __restrict__ bhh, int i,
    uint32 (&wr_)[128], uint32 (&wz_)[128], uint32 (&wn_)[128],
    float& br_, float& bz_, float& bn_)
{
  const float* pr = whh + i * 256;
  const float* pz = whh + (256 + i) * 256;
  const float* pn = whh + (512 + i) * 256;
#pragma unroll
  for (int c = 0; c < 128; ++c) {
    wr_[c] = pack_h2(pr[2*c], pr[2*c+1]);
    wz_[c] = pack_h2(pz[2*c], pz[2*c+1]);
    wn_[c] = pack_h2(pn[2*c], pn[2*c+1]);
  }
  br_ = bhh[i]; bz_ = bhh[256 + i]; bn_ = bhh[512 + i];
}

// 256 sequential GRU cells, fully lane-local except the h broadcast via LDS.
// One barrier per cell.
template<bool RELU>
__device__ __forceinline__ void run_cells(
    const float* __restrict__ xp, float* __restrict__ dst,
    const uint32 (&wr_)[128], const uint32 (&wz_)[128], const uint32 (&wn_)[128],
    float br_, float bz_, float bn_, float& h_reg, int i, u16* h16s)
{
  const uint4* h4 = (const uint4*)h16s;
  for (int t = 0; t < 256; ++t) {
    const float* xpt = xp + t * 768;
    float xr = xpt[i], xz = xpt[256 + i], xn = xpt[512 + i];
    float ar0 = 0.f, ar1 = 0.f, az0 = 0.f, az1 = 0.f, an0 = 0.f, an1 = 0.f;
#pragma unroll
    for (int c = 0; c < 32; ++c) {
      uint4 hp = h4[c];                          // LDS broadcast (same addr all lanes)
      ar0 = fdot2f(wr_[4*c+0], hp.x, ar0); ar1 = fdot2f(wr_[4*c+1], hp.y, ar1);
      ar0 = fdot2f(wr_[4*c+2], hp.z, ar0); ar1 = fdot2f(wr_[4*c+3], hp.w, ar1);
      az0 = fdot2f(wz_[4*c+0], hp.x, az0); az1 = fdot2f(wz_[4*c+1], hp.y, az1);
      az0 = fdot2f(wz_[4*c+2], hp.z, az0); az1 = fdot2f(wz_[4*c+3], hp.w, az1);
      an0 = fdot2f(wn_[4*c+0], hp.x, an0); an1 = fdot2f(wn_[4*c+1], hp.y, an1);
      an0 = fdot2f(wn_[4*c+2], hp.z, an0); an1 = fdot2f(wn_[4*c+3], hp.w, an1);
    }
    float r  = sigm(xr + ar0 + ar1 + br_);
    float z  = sigm(xz + az0 + az1 + bz_);
    float n  = tanhf(xn + r * (an0 + an1 + bn_));
    float hnew = (1.0f - z) * n + z * h_reg;
    h_reg = hnew;
    __syncthreads();                             // all lanes done reading old h
    h16s[i] = __builtin_bit_cast(u16, (_Float16)hnew);
    dst[t * 256 + i] = RELU ? fmaxf(hnew, 0.0f) : hnew;
    __syncthreads();                             // new h visible
  }
}

// helper-WG input projection: xpo[t][o] = sum_k src[t][k]*wih[o][k] + bih[o]
// one WG handles 4 t's, all 768 outputs. 256 threads.
__device__ __forceinline__ void xp_gemm(
    const float* __restrict__ src, const float* __restrict__ wih,
    const float* __restrict__ bih, float* __restrict__ xpo,
    int wgi, int tid, float (&XcL)[4][256])
{
  const int t0 = wgi * 4;
  for (int r = tid; r < 1024; r += NTH) XcL[r >> 8][r & 255] = src[t0 * 256 + r];
  __syncthreads();
  for (int o = tid; o < 768; o += NTH) {
    const float* wr = wih + o * 256;
    float a0 = 0.f, a1 = 0.f, a2 = 0.f, a3 = 0.f;
#pragma unroll 4
    for (int k = 0; k < 256; ++k) {
      float w = wr[k];
      a0 += w * XcL[0][k]; a1 += w * XcL[1][k];
      a2 += w * XcL[2][k]; a3 += w * XcL[3][k];
    }
    float b = bih[o];
    xpo[(t0+0)*768+o] = a0+b; xpo[(t0+1)*768+o] = a1+b;
    xpo[(t0+2)*768+o] = a2+b; xpo[(t0+3)*768+o] = a3+b;
  }
  __syncthreads();
}

extern "C" __global__ void __launch_bounds__(NTH, 1)
sed_kernel(const float* __restrict__ X,    const float* __restrict__ w1,
           const float* __restrict__ b1,   const float* __restrict__ w2,
           const float* __restrict__ b2,
           const float* __restrict__ ewih, const float* __restrict__ ewhh,
           const float* __restrict__ ebih, const float* __restrict__ ebhh,
           const float* __restrict__ dwih, const float* __restrict__ dwhh,
           const float* __restrict__ dbih, const float* __restrict__ dbhh,
           const float* __restrict__ fcw,  const float* __restrict__ fcb,
           float* __restrict__ out, unsigned char* __restrict__ ws)
{
  const int tid = threadIdx.x;
  const int wg  = blockIdx.x;
  uint32* bar_cnt = (uint32*)(ws);
  uint32* bar_rel = (uint32*)(ws + 128);
  float* xp = (float*)(ws + OFF_XP);
  float* Xc = (float*)(ws + OFF_XC);
  float* D  = (float*)(ws + OFF_D);
  float* y1 = (float*)(ws + OFF_Y1);

  __shared__ __align__(16) u16 h16s[256];
  __shared__ float XcL[4][256];
  __shared__ float hv[256], red[256], abuf[256], cbuf[256], pbuf[256];
  __shared__ float lbuf[26*8], la[32];

  unsigned round_ = 0;
  auto gbar = [&]() {
    __syncthreads();
    if (tid == 0) {
      unsigned old = __hip_atomic_fetch_add(bar_cnt, 1u, __ATOMIC_ACQ_REL,
                                            __HIP_MEMORY_SCOPE_AGENT);
      unsigned tgt = (round_ + 1u) * (unsigned)NWG;
      if (old + 1u == tgt)
        __hip_atomic_store(bar_rel, round_ + 1u, __ATOMIC_RELEASE,
                           __HIP_MEMORY_SCOPE_AGENT);
      while (__hip_atomic_load(bar_rel, __ATOMIC_ACQUIRE,
                               __HIP_MEMORY_SCOPE_AGENT) < round_ + 1u)
        __builtin_amdgcn_s_sleep(2);
    }
    round_ += 1u;
    __syncthreads();
  };

  const int i = tid;                 // 0..255: owned hidden unit
  uint32 wr_[128], wz_[128], wn_[128];
  float br_ = 0.f, bz_ = 0.f, bn_ = 0.f, h_reg = 0.f;

  // ---- P0a: y1[j][c] = w1[j]*x[c] + b1[j]   [128][512]
  for (int idx = wg * NTH + tid; idx < 128 * 512; idx += NWG * NTH) {
    int j = idx >> 9, c = idx & 511;
    y1[idx] = w1[j] * X[c] + b1[j];
  }
  gbar();

  // ---- P0b: seq[t][d] = y2[d][2t] (only even cols of y2 needed)
  for (int idx = wg * NTH + tid; idx < 256 * 256; idx += NWG * NTH) {
    int d = idx & 255, t = idx >> 8;
    const float* w2r = w2 + d * 128;
    float acc = b2[d];
#pragma unroll 4
    for (int j = 0; j < 128; ++j) acc += w2r[j] * y1[j * 512 + 2 * t];
    Xc[t * 256 + d] = acc;
  }
  gbar();

  // ---- P0c: helpers xp_enc = seq @ ewih^T + ebih ; WG0 loads enc W_hh regs
  if (wg == 0) load_weights(ewhh, ebhh, i, wr_, wz_, wn_, br_, bz_, bn_);
  else         xp_gemm(Xc, ewih, ebih, xp, wg - 1, tid, XcL);
  gbar();

  // ---- P1: encoder (256 cells), writes relu(h) into Xc (=Xr)
  if (wg == 0) {
    h16s[tid] = 0;
    h_reg = 0.f;
    __syncthreads();
    run_cells<true>(xp, Xc, wr_, wz_, wn_, br_, bz_, bn_, h_reg, i, h16s);
  }
  gbar();

  // ---- P2: helpers xp^0 = Xr @ dwih^T + dbih ; WG0 loads dec W_hh regs
  if (wg == 0) load_weights(dwhh, dbhh, i, wr_, wz_, wn_, br_, bz_, bn_);
  else         xp_gemm(Xc, dwih, dbih, xp, wg - 1, tid, XcL);
  gbar();

  // ---- decoder: 256 outer rows
  for (int k = 0; k < 256; ++k) {
    // phase 1: WG0 runs the 256 sequential cells of row k (h carries across rows)
    if (wg == 0)
      run_cells<false>(xp, D, wr_, wz_, wn_, br_, bz_, bn_, h_reg, i, h16s);
    gbar();

    // phase 2: helpers build xp^{k+1} from D; WG0 does attention + output row k
    if (wg == 0) {
      hv[tid] = D[255 * 256 + tid];              // h_new vector
      __syncthreads();
      // s_t = D[t,:]·h_new
      {
        const float* dr = D + tid * 256;
        float p = 0.f;
#pragma unroll 4
        for (int q = 0; q < 256; ++q) p += dr[q] * hv[q];
        pbuf[tid] = p; red[tid] = p;
      }
      __syncthreads();
      for (int st = 128; st > 0; st >>= 1) {
        if (tid < st) red[tid] = fmaxf(red[tid], red[tid + st]);
        __syncthreads();
      }
      float m = red[0];
      __syncthreads();
      { float e = expf(pbuf[tid] - m); abuf[tid] = e; red[tid] = e; }
      __syncthreads();
      for (int st = 128; st > 0; st >>= 1) {
        if (tid < st) red[tid] += red[tid + st];
        __syncthreads();
      }
      float inv = 1.0f / red[0];
      __syncthreads();
      abuf[tid] *= inv;
      __syncthreads();
      // c[i] = a[0]*D[0,i] + sum_{t=1..255} a[t-1]*D[t,i]
      {
        float acc = abuf[0] * D[tid];
        for (int t = 1; t < 256; ++t) acc += abuf[t - 1] * D[t * 256 + tid];
        cbuf[tid] = acc;
      }
      __syncthreads();
      // logits: fc_w @ [h_new, c] + fc_b  (26 outputs, 8 partials each)
      if (tid < 26 * 8) {
        int j = tid >> 3, sgm = tid & 7;
        const float* fr   = fcw + j * 512 + sgm * 64;
        const float* vsrc = (sgm < 4) ? (hv + sgm * 64) : (cbuf + (sgm - 4) * 64);
        float p = 0.f;
#pragma unroll 4
        for (int q = 0; q < 64; ++q) p += fr[q] * vsrc[q];
        lbuf[tid] = p;
      }
      __syncthreads();
      if (tid < 26) {
        float l = fcb[tid];
#pragma unroll
        for (int s = 0; s < 8; ++s) l += lbuf[tid * 8 + s];
        la[tid] = l;
      }
      __syncthreads();
      if (tid == 0) {
        float m2 = la[0];
        for (int j = 1; j < 26; ++j) m2 = fmaxf(m2, la[j]);
        float sm = 0.f;
        for (int j = 0; j < 26; ++j) { float e = expf(la[j] - m2); la[j] = e; sm += e; }
        float ii = 1.0f / sm;
        for (int j = 0; j < 26; ++j) la[j] *= ii;
      }
      __syncthreads();
      if (tid < 26) out[k * 26 + tid] = la[tid];
      __syncthreads();
    } else if (k < 255) {
      xp_gemm(D, dwih, dbih, xp, wg - 1, tid, XcL);
    }
    gbar();
  }
}

extern "C" void kernel_launch(void* const* d_in, const int* in_sizes, int n_in,
                              void* d_out, int out_size, void* d_ws, size_t ws_size,
                              hipStream_t stream) {
  (void)in_sizes; (void)n_in; (void)out_size; (void)ws_size;
  // zero the grid-barrier counters (ws is poisoned 0xAA before every launch)
  hipMemsetAsync(d_ws, 0, 1024, stream);
  sed_kernel<<<NWG, NTH, 0, stream>>>(
      (const float*)d_in[0],  (const float*)d_in[1],  (const float*)d_in[2],
      (const float*)d_in[3],  (const float*)d_in[4],  (const float*)d_in[5],
      (const float*)d_in[6],  (const float*)d_in[7],  (const float*)d_in[8],
      (const float*)d_in[9],  (const float*)d_in[10], (const float*)d_in[11],
      (const float*)d_in[12], (const float*)d_in[13], (const float*)d_in[14],
      (float*)d_out, (unsigned char*)d_ws);
}

// Round 3
// 125776.025 us; speedup vs baseline: 8.7227x; 8.7227x over previous
//
#include <hip/hip_runtime.h>
#include <hip/hip_fp16.h>
#include <math.h>

typedef unsigned int  uint32;
typedef unsigned short u16;

#define NWG 65          // 1 sequential WG + 64 helper WGs
#define NTH 512

// workspace layout (bytes)
#define OFF_XP   1024u                        // xp buffer [256][768] f32
#define OFF_XC   (OFF_XP + 256u*768u*4u)      // Xc / seq / Xr buffer [256][256] f32
#define OFF_D    (OFF_XC + 256u*256u*4u)      // dec_out row buffer [256][256] f32
#define OFF_Y1   (OFF_D  + 256u*256u*4u)      // y1 [128][512] f32

typedef _Float16 half2_t __attribute__((ext_vector_type(2)));

__device__ __forceinline__ float fdot2f(uint32 w, uint32 h, float acc) {
#if __has_builtin(__builtin_amdgcn_fdot2)
  return __builtin_amdgcn_fdot2(__builtin_bit_cast(half2_t, w),
                                __builtin_bit_cast(half2_t, h), acc, false);
#else
  half2_t a = __builtin_bit_cast(half2_t, w);
  half2_t b = __builtin_bit_cast(half2_t, h);
  return acc + (float)a[0]*(float)b[0] + (float)a[1]*(float)b[1];
#endif
}

__device__ __forceinline__ uint32 pack_h2(float x, float y) {
  _Float16 hx = (_Float16)x, hy = (_Float16)y;
  u16 ux = __builtin_bit_cast(u16, hx);
  u16 uy = __builtin_bit_cast(u16, hy);
  return (uint32)ux | ((uint32)uy << 16);
}

__device__ __forceinline__ float sigm(float x) { return 1.0f/(1.0f + expf(-x)); }

// Load one GRU's W_hh (f32 [768][256]) into per-lane packed-f16 registers.
// lane (cls=0, i): full row r_i + n_i[0:128]   = 128 + 64 packed words
// lane (cls=1, i): full row z_i + n_i[128:256] = 128 + 64 packed words
// 192 weight VGPRs/lane — fits the 256 ArchVGPR cap at 2 waves/SIMD.
__device__ __forceinline__ void load_weights(
    const float* __restrict__ whh, const float* __restrict__ bhh,
    int i, int cls, uint32 (&wfull)[128], uint32 (&whalf)[64],
    float& bfull, float& bhalfn)
{
  const int rfull = (cls == 0) ? i : (256 + i);
  const float* wr = whh + rfull * 256;
#pragma unroll
  for (int c = 0; c < 128; ++c) wfull[c] = pack_h2(wr[2*c], wr[2*c+1]);
  const float* wn = whh + (512 + i) * 256 + cls * 128;
#pragma unroll
  for (int c = 0; c < 64; ++c) whalf[c] = pack_h2(wn[2*c], wn[2*c+1]);
  bfull  = bhh[rfull];
  bhalfn = (cls == 0) ? bhh[512 + i] : 0.0f;
}

// 256 sequential GRU cells. h carried f32 in cls0 lanes + f16 copy in LDS.
template<bool RELU>
__device__ __forceinline__ void run_cells(
    const float* __restrict__ xp, float* __restrict__ dst,
    const uint32 (&wfull)[128], const uint32 (&whalf)[64],
    float bfull, float bhalfn, float& h_reg, int i, int cls,
    u16* h16s, float* zbuf, float* nbuf)
{
  const uint4* h4 = (const uint4*)h16s;
  const int hoff = cls ? 16 : 0;   // which half of h the n-half-row needs
  for (int t = 0; t < 256; ++t) {
    const float* xpt = xp + t * 768;
    float xA = (cls == 0) ? xpt[i] : xpt[256 + i];       // xr or xz (b_ih folded in)
    float xB = (cls == 0) ? xpt[512 + i] : 0.0f;         // xn (heavy only)
    float a0 = 0.f, a1 = 0.f, b0 = 0.f, b1 = 0.f;
#pragma unroll
    for (int c = 0; c < 32; ++c) {                       // full row: K=256
      uint4 hp = h4[c];                                  // LDS broadcast
      a0 = fdot2f(wfull[4*c+0], hp.x, a0);
      a1 = fdot2f(wfull[4*c+1], hp.y, a1);
      a0 = fdot2f(wfull[4*c+2], hp.z, a0);
      a1 = fdot2f(wfull[4*c+3], hp.w, a1);
    }
#pragma unroll
    for (int c = 0; c < 16; ++c) {                       // n half-row: K=128
      uint4 hp = h4[hoff + c];
      b0 = fdot2f(whalf[4*c+0], hp.x, b0);
      b1 = fdot2f(whalf[4*c+1], hp.y, b1);
      b0 = fdot2f(whalf[4*c+2], hp.z, b0);
      b1 = fdot2f(whalf[4*c+3], hp.w, b1);
    }
    float gfull = a0 + a1 + bfull;   // Wr·h+br (cls0) | Wz·h+bz (cls1)
    float ghalf = b0 + b1;           // partial Wn·h
    if (cls) {
      zbuf[i] = sigm(xA + gfull);    // z_i
      nbuf[i] = ghalf;               // n partial (k=128..255)
    }
    __syncthreads();
    if (!cls) {
      float r    = sigm(xA + gfull);
      float hn   = ghalf + nbuf[i] + bhalfn;             // Wn·h + b_hh_n
      float n    = tanhf(xB + r * hn);
      float z    = zbuf[i];
      float hnew = (1.0f - z) * n + z * h_reg;
      h_reg = hnew;
      h16s[i] = __builtin_bit_cast(u16, (_Float16)hnew); // raw h for next cell
      dst[t * 256 + i] = RELU ? fmaxf(hnew, 0.0f) : hnew;
    }
    __syncthreads();
  }
}

// helper-WG input projection: xpo[t][o] = sum_k src[t][k]*wih[o][k] + bih[o]
// one WG handles 4 t's, all 768 outputs.
__device__ __forceinline__ void xp_gemm(
    const float* __restrict__ src, const float* __restrict__ wih,
    const float* __restrict__ bih, float* __restrict__ xpo,
    int wgi, int tid, float (&XcL)[4][256])
{
  const int t0 = wgi * 4;
  for (int r = tid; r < 1024; r += NTH) XcL[r >> 8][r & 255] = src[t0 * 256 + r];
  __syncthreads();
  for (int o = tid; o < 768; o += NTH) {
    const float* wr = wih + o * 256;
    float a0 = 0.f, a1 = 0.f, a2 = 0.f, a3 = 0.f;
#pragma unroll 4
    for (int k = 0; k < 256; ++k) {
      float w = wr[k];
      a0 += w * XcL[0][k]; a1 += w * XcL[1][k];
      a2 += w * XcL[2][k]; a3 += w * XcL[3][k];
    }
    float b = bih[o];
    xpo[(t0+0)*768+o] = a0+b; xpo[(t0+1)*768+o] = a1+b;
    xpo[(t0+2)*768+o] = a2+b; xpo[(t0+3)*768+o] = a3+b;
  }
  __syncthreads();
}

extern "C" __global__ void __launch_bounds__(NTH, 1)   // 1 block/CU -> 2 waves/SIMD -> 256-VGPR cap
sed_kernel(const float* __restrict__ X,    const float* __restrict__ w1,
           const float* __restrict__ b1,   const float* __restrict__ w2,
           const float* __restrict__ b2,
           const float* __restrict__ ewih, const float* __restrict__ ewhh,
           const float* __restrict__ ebih, const float* __restrict__ ebhh,
           const float* __restrict__ dwih, const float* __restrict__ dwhh,
           const float* __restrict__ dbih, const float* __restrict__ dbhh,
           const float* __restrict__ fcw,  const float* __restrict__ fcb,
           float* __restrict__ out, unsigned char* __restrict__ ws)
{
  const int tid = threadIdx.x;
  const int wg  = blockIdx.x;
  uint32* bar_cnt = (uint32*)(ws);
  uint32* bar_rel = (uint32*)(ws + 128);
  float* xp = (float*)(ws + OFF_XP);
  float* Xc = (float*)(ws + OFF_XC);
  float* D  = (float*)(ws + OFF_D);
  float* y1 = (float*)(ws + OFF_Y1);

  __shared__ __align__(16) u16 h16s[256];
  __shared__ float zbuf[256], nbuf[256];
  __shared__ float XcL[4][256];
  __shared__ float hv[256], red[256], abuf[256], cbuf[256], pbuf[512];
  __shared__ float lbuf[26*8], la[32];

  unsigned round_ = 0;
  auto gbar = [&]() {
    __syncthreads();
    if (tid == 0) {
      unsigned old = __hip_atomic_fetch_add(bar_cnt, 1u, __ATOMIC_ACQ_REL,
                                            __HIP_MEMORY_SCOPE_AGENT);
      unsigned tgt = (round_ + 1u) * (unsigned)NWG;
      if (old + 1u == tgt)
        __hip_atomic_store(bar_rel, round_ + 1u, __ATOMIC_RELEASE,
                           __HIP_MEMORY_SCOPE_AGENT);
      while (__hip_atomic_load(bar_rel, __ATOMIC_ACQUIRE,
                               __HIP_MEMORY_SCOPE_AGENT) < round_ + 1u)
        __builtin_amdgcn_s_sleep(2);
    }
    round_ += 1u;
    __syncthreads();
  };

  const int i   = tid & 255;
  const int cls = tid >> 8;
  uint32 wfull[128]; uint32 whalf[64];
  float bfull = 0.f, bhalfn = 0.f, h_reg = 0.f;

  // ---- P0a: y1[j][c] = w1[j]*x[c] + b1[j]   [128][512]
  for (int idx = wg * NTH + tid; idx < 128 * 512; idx += NWG * NTH) {
    int j = idx >> 9, c = idx & 511;
    y1[idx] = w1[j] * X[c] + b1[j];
  }
  gbar();

  // ---- P0b: seq[t][d] = y2[d][2t] (only even cols of y2 needed)
  for (int idx = wg * NTH + tid; idx < 256 * 256; idx += NWG * NTH) {
    int d = idx & 255, t = idx >> 8;
    const float* w2r = w2 + d * 128;
    float acc = b2[d];
#pragma unroll 4
    for (int j = 0; j < 128; ++j) acc += w2r[j] * y1[j * 512 + 2 * t];
    Xc[t * 256 + d] = acc;
  }
  gbar();

  // ---- P0c: helpers xp_enc = seq @ ewih^T + ebih ; WG0 loads enc W_hh regs
  if (wg == 0) load_weights(ewhh, ebhh, i, cls, wfull, whalf, bfull, bhalfn);
  else         xp_gemm(Xc, ewih, ebih, xp, wg - 1, tid, XcL);
  gbar();

  // ---- P1: encoder (256 cells), writes relu(h) into Xc (=Xr)
  if (wg == 0) {
    if (tid < 256) h16s[tid] = 0;
    h_reg = 0.f;
    __syncthreads();
    run_cells<true>(xp, Xc, wfull, whalf, bfull, bhalfn, h_reg, i, cls,
                    h16s, zbuf, nbuf);
  }
  gbar();

  // ---- P2: helpers xp^0 = Xr @ dwih^T + dbih ; WG0 loads dec W_hh regs
  if (wg == 0) load_weights(dwhh, dbhh, i, cls, wfull, whalf, bfull, bhalfn);
  else         xp_gemm(Xc, dwih, dbih, xp, wg - 1, tid, XcL);
  gbar();

  // ---- decoder: 256 outer rows
  for (int k = 0; k < 256; ++k) {
    // phase 1: WG0 runs the 256 sequential cells of row k (h carries across rows)
    if (wg == 0)
      run_cells<false>(xp, D, wfull, whalf, bfull, bhalfn, h_reg, i, cls,
                       h16s, zbuf, nbuf);
    gbar();

    // phase 2: helpers build xp^{k+1} from D; WG0 does attention + output row k
    if (wg == 0) {
      // h_new vector
      if (tid < 256) hv[tid] = D[255 * 256 + tid];
      __syncthreads();
      // s_t = D[t,:]·h_new  (split each dot across 2 threads)
      {
        int t = tid & 255, hh = tid >> 8;
        const float* dr  = D + t * 256 + hh * 128;
        const float* hvp = hv + hh * 128;
        float p = 0.f;
#pragma unroll 4
        for (int q = 0; q < 128; ++q) p += dr[q] * hvp[q];
        pbuf[hh * 256 + t] = p;
      }
      __syncthreads();
      if (tid < 256) { float s = pbuf[tid] + pbuf[256 + tid]; pbuf[tid] = s; red[tid] = s; }
      __syncthreads();
      for (int st = 128; st > 0; st >>= 1) {
        if (tid < st) red[tid] = fmaxf(red[tid], red[tid + st]);
        __syncthreads();
      }
      float m = red[0];
      __syncthreads();
      if (tid < 256) { float e = expf(pbuf[tid] - m); abuf[tid] = e; red[tid] = e; }
      __syncthreads();
      for (int st = 128; st > 0; st >>= 1) {
        if (tid < st) red[tid] += red[tid + st];
        __syncthreads();
      }
      float inv = 1.0f / red[0];
      __syncthreads();
      if (tid < 256) abuf[tid] *= inv;
      __syncthreads();
      // c[i] = a[0]*D[0,i] + sum_{t=1..255} a[t-1]*D[t,i]
      if (tid < 256) {
        float acc = abuf[0] * D[tid];
        for (int t = 1; t < 256; ++t) acc += abuf[t - 1] * D[t * 256 + tid];
        cbuf[tid] = acc;
      }
      __syncthreads();
      // logits: fc_w @ [h_new, c] + fc_b  (26 outputs, 8 partials each)
      if (tid < 26 * 8) {
        int j = tid >> 3, sgm = tid & 7;
        const float* fr   = fcw + j * 512 + sgm * 64;
        const float* vsrc = (sgm < 4) ? (hv + sgm * 64) : (cbuf + (sgm - 4) * 64);
        float p = 0.f;
#pragma unroll 4
        for (int q = 0; q < 64; ++q) p += fr[q] * vsrc[q];
        lbuf[tid] = p;
      }
      __syncthreads();
      if (tid < 26) {
        float l = fcb[tid];
#pragma unroll
        for (int s = 0; s < 8; ++s) l += lbuf[tid * 8 + s];
        la[tid] = l;
      }
      __syncthreads();
      if (tid == 0) {
        float m2 = la[0];
        for (int j = 1; j < 26; ++j) m2 = fmaxf(m2, la[j]);
        float sm = 0.f;
        for (int j = 0; j < 26; ++j) { float e = expf(la[j] - m2); la[j] = e; sm += e; }
        float ii = 1.0f / sm;
        for (int j = 0; j < 26; ++j) la[j] *= ii;
      }
      __syncthreads();
      if (tid < 26) out[k * 26 + tid] = la[tid];
      __syncthreads();
    } else if (k < 255) {
      xp_gemm(D, dwih, dbih, xp, wg - 1, tid, XcL);
    }
    gbar();
  }
}

extern "C" void kernel_launch(void* const* d_in, const int* in_sizes, int n_in,
                              void* d_out, int out_size, void* d_ws, size_t ws_size,
                              hipStream_t stream) {
  (void)in_sizes; (void)n_in; (void)out_size; (void)ws_size;
  // zero the grid-barrier counters (ws is poisoned 0xAA before every launch)
  hipMemsetAsync(d_ws, 0, 1024, stream);
  sed_kernel<<<NWG, NTH, 0, stream>>>(
      (const float*)d_in[0],  (const float*)d_in[1],  (const float*)d_in[2],
      (const float*)d_in[3],  (const float*)d_in[4],  (const float*)d_in[5],
      (const float*)d_in[6],  (const float*)d_in[7],  (const float*)d_in[8],
      (const float*)d_in[9],  (const float*)d_in[10], (const float*)d_in[11],
      (const float*)d_in[12], (const float*)d_in[13], (const float*)d_in[14],
      (float*)d_out, (unsigned char*)d_ws);
}